// Round 1
// baseline (125.380 us; speedup 1.0000x reference)
//
#include <hip/hip_runtime.h>
#include <math.h>

#define BB   4
#define MM   1024
#define NN   1024
#define DD   9
#define KSEL 16
#define NROW (BB * MM)        // 4096 rows; wave r handles intra-row r AND outer-row r
#define NSLOT (2 * NROW)

// Workspace. yT first => 16B-aligned float4 planes. Every field written before
// read each launch (setup zeroes ticket; dist writes every rowsum slot).
// Harness re-poisons the full d_ws (2 x ~39us fills) inside the timed window:
// ~80us session floor we cannot touch. This version attacks the ~17us we own:
// 4 launches -> 2, and halves dist's L2 plane traffic by pairing rows.
struct Ws {
  float yT[BB * DD * NN];     // [b][p][j] SoA planes
  float qy[BB * NN];          // y_j^T Cinv y_j
  float rowsum[NSLOT];        // [0,4096): intra sums; [4096,8192): outer sums
  float cnt;
  float mean[DD];
  float cinv[DD * DD];
  unsigned int ticket;        // zeroed by setup_kernel each launch
};

// ---------------------------------------------------------------------------
// Kernel A: ONE block x 512. Phase 1: masked moment partials (8 rows/thread,
// float4-staged). Phase 2: wave 0 fp64 Gauss-Jordan (cov of ~2048 N(0,1)
// samples is SPD, diag~1 => no pivoting needed, pinv == inverse). Phase 3:
// SoA transpose + qy for all 4096 outputs (8 consecutive j/thread, float4
// loads AND float4 stores). Single block => only __syncthreads, no
// cross-block sync. Also zero-inits the dist ticket (poison-proof).
// ---------------------------------------------------------------------------
__global__ __launch_bounds__(512) void setup_kernel(
    const float* __restrict__ outputs, const float* __restrict__ targets,
    const int* __restrict__ mask, Ws* __restrict__ ws) {
  const int tid = threadIdx.x;  // 0..511
  __shared__ float part[8][55];
  __shared__ double Sd[55];
  __shared__ float Cs[DD * DD];

  // ---- phase 1: moments over rows 8t..8t+7 (72 floats = 18 float4, exact)
  float acc[55];
#pragma unroll
  for (int k = 0; k < 55; ++k) acc[k] = 0.f;
  {
    const float4* tp = (const float4*)targets + 18 * tid;
    float4 st4[18];
#pragma unroll
    for (int i = 0; i < 18; ++i) st4[i] = tp[i];
    const float* f = (const float*)st4;
    const int4 m0 = ((const int4*)mask)[2 * tid];
    const int4 m1 = ((const int4*)mask)[2 * tid + 1];
    const int mk[8] = {m0.x, m0.y, m0.z, m0.w, m1.x, m1.y, m1.z, m1.w};
#pragma unroll
    for (int rr = 0; rr < 8; ++rr) {
      if (mk[rr] != 0) {
        const float* t = f + rr * DD;
        acc[0] += 1.f;
#pragma unroll
        for (int k = 0; k < DD; ++k) acc[1 + k] += t[k];
        int u = 10;
#pragma unroll
        for (int p = 0; p < DD; ++p)
#pragma unroll
          for (int q = p; q < DD; ++q) acc[u++] += t[p] * t[q];
      }
    }
  }
#pragma unroll
  for (int k = 0; k < 55; ++k) {
    float v = acc[k];
#pragma unroll
    for (int off = 32; off > 0; off >>= 1) v += __shfl_down(v, off, 64);
    if ((tid & 63) == 0) part[tid >> 6][k] = v;
  }
  if (tid == 0) ws->ticket = 0u;  // kernel-boundary coherence covers dist's atomic
  __syncthreads();

  if (tid < 55) {
    double s = 0.0;
#pragma unroll
    for (int w = 0; w < 8; ++w) s += (double)part[w][tid];
    Sd[tid] = s;
  }
  __syncthreads();

  // ---- phase 2: fp64 Gauss-Jordan on wave 0 (lane p owns augmented row p)
  if (tid < 64) {
    const int lane = tid;
    const double cnt = Sd[0];
    const int p = (lane < DD) ? lane : 0;  // junk lanes mirror row 0
    double row[2 * DD];
    {
      const double mu_p = Sd[1 + p] / cnt;
#pragma unroll
      for (int q = 0; q < DD; ++q) {
        const int pp = (p < q) ? p : q;
        const int qq = (p < q) ? q : p;
        const int idx = 10 + 9 * pp - (pp * (pp - 1)) / 2 + (qq - pp);
        row[q] = (Sd[idx] - cnt * mu_p * (Sd[1 + q] / cnt)) / (cnt - 1.0);
        row[DD + q] = (p == q) ? 1.0 : 0.0;
      }
    }
#pragma unroll
    for (int c = 0; c < DD; ++c) {
      const double diag = __shfl(row[c], c, 64);
      const double dinv = 1.0 / diag;
      if (lane == c) {
#pragma unroll
        for (int q = 0; q < 2 * DD; ++q) row[q] *= dinv;
      }
      const double f = (lane == c) ? 0.0 : row[c];
#pragma unroll
      for (int q = 0; q < 2 * DD; ++q) {
        const double pv = __shfl(row[q], c, 64);
        row[q] -= f * pv;
      }
    }
    if (lane < DD) {
#pragma unroll
      for (int q = 0; q < DD; ++q) {
        const float cf = (float)row[DD + q];
        Cs[lane * DD + q] = cf;
        ws->cinv[lane * DD + q] = cf;
      }
    }
    if (lane == 0) {
      ws->cnt = (float)cnt;
#pragma unroll
      for (int q = 0; q < DD; ++q) ws->mean[q] = (float)(Sd[1 + q] / cnt);
    }
  }
  __syncthreads();

  // ---- phase 3: qy + SoA transpose, 8 consecutive j per thread
  {
    const int j0 = tid * 8;
    const int b = j0 >> 10;
    const int jj = j0 & (NN - 1);
    float C[DD * DD];
#pragma unroll
    for (int k = 0; k < DD * DD; ++k) C[k] = Cs[k];
    const float4* op4 = (const float4*)outputs + 18 * tid;
    float4 so4[18];
#pragma unroll
    for (int i = 0; i < 18; ++i) so4[i] = op4[i];
    const float* f = (const float*)so4;
#pragma unroll
    for (int g = 0; g < 2; ++g) {
      float qv[4];
#pragma unroll
      for (int rr = 0; rr < 4; ++rr) {
        const float* y = f + (g * 4 + rr) * DD;
        float qq = 0.f;
#pragma unroll
        for (int p = 0; p < DD; ++p) {
          float s = 0.f;
#pragma unroll
          for (int t = 0; t < DD; ++t) s += C[p * DD + t] * y[t];
          qq += y[p] * s;
        }
        qv[rr] = qq;
      }
#pragma unroll
      for (int p = 0; p < DD; ++p) {
        float4 o;
        o.x = f[(g * 4 + 0) * DD + p];
        o.y = f[(g * 4 + 1) * DD + p];
        o.z = f[(g * 4 + 2) * DD + p];
        o.w = f[(g * 4 + 3) * DD + p];
        *(float4*)(&ws->yT[(b * DD + p) * NN + jj + g * 4]) = o;
      }
      *(float4*)(&ws->qy[b * NN + jj + g * 4]) =
          make_float4(qv[0], qv[1], qv[2], qv[3]);
    }
  }
}

// ---------------------------------------------------------------------------
// Top-16-smallest sum over 1024 values (16/lane): per-lane bitonic sort +
// 6 shfl_xor half-cleaner rounds; re-merge skipped after the last round
// (half-cleaner output already holds exactly the top-16 multiset).
// ---------------------------------------------------------------------------
__device__ __forceinline__ float top16_sum(float (&v)[16]) {
#pragma unroll
  for (int k = 2; k <= 16; k <<= 1) {
#pragma unroll
    for (int j = k >> 1; j > 0; j >>= 1) {
#pragma unroll
      for (int i = 0; i < 16; ++i) {
        const int l = i ^ j;
        if (l > i) {
          const bool up = ((i & k) == 0);
          const float lo = fminf(v[i], v[l]);
          const float hi = fmaxf(v[i], v[l]);
          v[i] = up ? lo : hi;
          v[l] = up ? hi : lo;
        }
      }
    }
  }
#pragma unroll
  for (int off = 1; off < 64; off <<= 1) {
    float pr[16];
#pragma unroll
    for (int i = 0; i < 16; ++i) pr[i] = __shfl_xor(v[i], off, 64);
#pragma unroll
    for (int i = 0; i < 16; ++i) v[i] = fminf(v[i], pr[15 - i]);
    if (off < 32) {
#pragma unroll
      for (int j = 8; j > 0; j >>= 1) {
#pragma unroll
        for (int i = 0; i < 16; ++i) {
          const int l = i ^ j;
          if (l > i) {
            const float lo = fminf(v[i], v[l]);
            const float hi = fmaxf(v[i], v[l]);
            v[i] = lo;
            v[l] = hi;
          }
        }
      }
    }
  }
  float total = v[0];
#pragma unroll
  for (int k = 1; k < 16; ++k) total += v[k];
  return total;
}

// ---------------------------------------------------------------------------
// Kernel B: 1024 blocks x 256. One wave per row r handles BOTH the intra row
// (if unmasked) and the outer row => each yT/qy plane load feeds two
// accumulator sets, halving L2 traffic vs one-row-per-wave. Per-accumulator
// FMA order is unchanged from the previous version (bitwise-same distances).
// Last block (device-scope ticket) folds in the finalize reduction; rowsum
// crosses XCDs via agent-scope (sc1) stores/loads so non-coherent per-XCD
// L2s (which may hold poison) are bypassed.
// ---------------------------------------------------------------------------
__global__ __launch_bounds__(256, 4) void dist_kernel(
    const float* __restrict__ outputs, const float* __restrict__ targets,
    const int* __restrict__ mask, Ws* __restrict__ ws,
    float* __restrict__ out) {
  const int tid = threadIdx.x;
  const int wv = tid >> 6;
  const int lane = tid & 63;
  const int r = blockIdx.x * 4 + wv;  // 0..4095
  const int b = r >> 10;
  const bool live = (mask[r] != 0);   // wave-uniform

  // outer side: u = y_r + mean (reference subtracts mean from the DIFF)
  float ao[DD], wo[DD];
  float qa_o = 0.f;
#pragma unroll
  for (int k = 0; k < DD; ++k) ao[k] = outputs[r * DD + k] + ws->mean[k];
#pragma unroll
  for (int p = 0; p < DD; ++p) {
    float s = 0.f;
#pragma unroll
    for (int t = 0; t < DD; ++t) s += ws->cinv[p * DD + t] * ao[t];
    wo[p] = s;
    qa_o += ao[p] * s;
  }
  // intra side: a = t_r - mean
  float ai[DD], wi[DD];
  float qa_i = 0.f;
  if (live) {
#pragma unroll
    for (int k = 0; k < DD; ++k) ai[k] = targets[r * DD + k] - ws->mean[k];
#pragma unroll
    for (int p = 0; p < DD; ++p) {
      float s = 0.f;
#pragma unroll
      for (int t = 0; t < DD; ++t) s += ws->cinv[p * DD + t] * ai[t];
      wi[p] = s;
      qa_i += ai[p] * s;
    }
  }

  float vi[16], vo[16];
#pragma unroll
  for (int k = 0; k < 16; ++k) {
    vi[k] = 0.f;
    vo[k] = 0.f;
  }
  const float* __restrict__ yTb = ws->yT + (size_t)b * DD * NN;
  if (live) {
#pragma unroll
    for (int p = 0; p < DD; ++p) {
      const float4* __restrict__ pl = (const float4*)(yTb + (size_t)p * NN);
#pragma unroll
      for (int c = 0; c < 4; ++c) {
        const float4 y4 = pl[c * 64 + lane];
        vi[c * 4 + 0] += wi[p] * y4.x;
        vi[c * 4 + 1] += wi[p] * y4.y;
        vi[c * 4 + 2] += wi[p] * y4.z;
        vi[c * 4 + 3] += wi[p] * y4.w;
        vo[c * 4 + 0] += wo[p] * y4.x;
        vo[c * 4 + 1] += wo[p] * y4.y;
        vo[c * 4 + 2] += wo[p] * y4.z;
        vo[c * 4 + 3] += wo[p] * y4.w;
      }
    }
  } else {
#pragma unroll
    for (int p = 0; p < DD; ++p) {
      const float4* __restrict__ pl = (const float4*)(yTb + (size_t)p * NN);
#pragma unroll
      for (int c = 0; c < 4; ++c) {
        const float4 y4 = pl[c * 64 + lane];
        vo[c * 4 + 0] += wo[p] * y4.x;
        vo[c * 4 + 1] += wo[p] * y4.y;
        vo[c * 4 + 2] += wo[p] * y4.z;
        vo[c * 4 + 3] += wo[p] * y4.w;
      }
    }
  }
  {
    const float4* __restrict__ q4 = (const float4*)(ws->qy + (size_t)b * NN);
#pragma unroll
    for (int c = 0; c < 4; ++c) {
      const float4 qv = q4[c * 64 + lane];
      vo[c * 4 + 0] = qa_o + qv.x - 2.f * vo[c * 4 + 0];
      vo[c * 4 + 1] = qa_o + qv.y - 2.f * vo[c * 4 + 1];
      vo[c * 4 + 2] = qa_o + qv.z - 2.f * vo[c * 4 + 2];
      vo[c * 4 + 3] = qa_o + qv.w - 2.f * vo[c * 4 + 3];
      if (live) {
        vi[c * 4 + 0] = qa_i + qv.x - 2.f * vi[c * 4 + 0];
        vi[c * 4 + 1] = qa_i + qv.y - 2.f * vi[c * 4 + 1];
        vi[c * 4 + 2] = qa_i + qv.z - 2.f * vi[c * 4 + 2];
        vi[c * 4 + 3] = qa_i + qv.w - 2.f * vi[c * 4 + 3];
      }
    }
  }

  float si = 0.f;
  if (live) si = top16_sum(vi);
  const float so = top16_sum(vo);
  if (lane == 0) {
    __hip_atomic_store(&ws->rowsum[r], si, __ATOMIC_RELAXED,
                       __HIP_MEMORY_SCOPE_AGENT);
    __hip_atomic_store(&ws->rowsum[NROW + r], so, __ATOMIC_RELAXED,
                       __HIP_MEMORY_SCOPE_AGENT);
  }

  // ---- last-block finalize (syncthreads drains vmcnt => sc1 stores done)
  __syncthreads();
  __shared__ int slast;
  if (tid == 0) {
    const unsigned int old = __hip_atomic_fetch_add(
        &ws->ticket, 1u, __ATOMIC_ACQ_REL, __HIP_MEMORY_SCOPE_AGENT);
    slast = (old == (unsigned int)(gridDim.x - 1)) ? 1 : 0;
  }
  __syncthreads();
  if (slast != 0) {
    double li = 0.0, lo = 0.0;
    for (int k = tid; k < NROW; k += 256) {
      li += (double)__hip_atomic_load(&ws->rowsum[k], __ATOMIC_RELAXED,
                                      __HIP_MEMORY_SCOPE_AGENT);
      lo += (double)__hip_atomic_load(&ws->rowsum[NROW + k], __ATOMIC_RELAXED,
                                      __HIP_MEMORY_SCOPE_AGENT);
    }
#pragma unroll
    for (int off = 32; off > 0; off >>= 1) {
      li += __shfl_down(li, off, 64);
      lo += __shfl_down(lo, off, 64);
    }
    __shared__ double lds_i[4], lds_o[4];
    if ((tid & 63) == 0) {
      lds_i[tid >> 6] = li;
      lds_o[tid >> 6] = lo;
    }
    __syncthreads();
    if (tid == 0) {
      const double sI = lds_i[0] + lds_i[1] + lds_i[2] + lds_i[3];
      const double sO = lds_o[0] + lds_o[1] + lds_o[2] + lds_o[3];
      const float intra = (float)(sI / (double)ws->cnt);
      const float outer = (float)(sO / (double)(NROW * KSEL));
      out[0] = intra;
      out[1] = intra;
      out[2] = outer;
    }
  }
}

extern "C" void kernel_launch(void* const* d_in, const int* in_sizes, int n_in,
                              void* d_out, int out_size, void* d_ws,
                              size_t ws_size, hipStream_t stream) {
  const float* outputs = (const float*)d_in[0];  // (4,1024,9) f32
  const float* targets = (const float*)d_in[1];  // (4,1024,9) f32
  const int* mask = (const int*)d_in[2];         // (4,1024) int32
  Ws* ws = (Ws*)d_ws;
  float* out = (float*)d_out;

  setup_kernel<<<1, 512, 0, stream>>>(outputs, targets, mask, ws);
  dist_kernel<<<NROW / 4, 256, 0, stream>>>(outputs, targets, mask, ws, out);
}

// Round 2
// 119.436 us; speedup vs baseline: 1.0498x; 1.0498x over previous
//
#include <hip/hip_runtime.h>
#include <math.h>

#define BB   4
#define MM   1024
#define NN   1024
#define DD   9
#define KSEL 16
#define NROW (BB * MM)        // 4096 rows; wave r handles intra-row r AND outer-row r
#define NSLOT (2 * NROW)

// Workspace. yT first => 16B-aligned float4 planes. Every field written before
// read each launch (setup zeroes ticket; dist writes every rowsum slot).
// Harness re-poisons the full d_ws (2 x ~39us fills) inside the timed window:
// ~78us session floor we cannot touch. We own: setup (~2us) + dist + gaps.
// R1 lesson: __launch_bounds__(256,4) capped VGPRs at 64 -> 16.7MB spill
// writes -> dist 46.5us. This round: uncapped (256) like the proven R0 dist.
struct Ws {
  float yT[BB * DD * NN];     // [b][p][j] SoA planes
  float qy[BB * NN];          // y_j^T Cinv y_j
  float rowsum[NSLOT];        // [0,4096): intra sums; [4096,8192): outer sums
  float cnt;
  float mean[DD];
  float cinv[DD * DD];
  unsigned int ticket;        // zeroed by setup_kernel each launch
};

// ---------------------------------------------------------------------------
// Kernel A: ONE block x 512. Phase 1: masked moment partials (8 rows/thread,
// float4-staged). Phase 2: wave 0 fp64 Gauss-Jordan (cov of ~2048 N(0,1)
// samples is SPD, diag~1 => no pivoting needed, pinv == inverse). Phase 3:
// SoA transpose + qy for all 4096 outputs (8 consecutive j/thread, float4
// loads AND float4 stores). Single block => only __syncthreads, no
// cross-block sync. Also zero-inits the dist ticket (poison-proof).
// ---------------------------------------------------------------------------
__global__ __launch_bounds__(512) void setup_kernel(
    const float* __restrict__ outputs, const float* __restrict__ targets,
    const int* __restrict__ mask, Ws* __restrict__ ws) {
  const int tid = threadIdx.x;  // 0..511
  __shared__ float part[8][55];
  __shared__ double Sd[55];
  __shared__ float Cs[DD * DD];

  // ---- phase 1: moments over rows 8t..8t+7 (72 floats = 18 float4, exact)
  float acc[55];
#pragma unroll
  for (int k = 0; k < 55; ++k) acc[k] = 0.f;
  {
    const float4* tp = (const float4*)targets + 18 * tid;
    float4 st4[18];
#pragma unroll
    for (int i = 0; i < 18; ++i) st4[i] = tp[i];
    const float* f = (const float*)st4;
    const int4 m0 = ((const int4*)mask)[2 * tid];
    const int4 m1 = ((const int4*)mask)[2 * tid + 1];
    const int mk[8] = {m0.x, m0.y, m0.z, m0.w, m1.x, m1.y, m1.z, m1.w};
#pragma unroll
    for (int rr = 0; rr < 8; ++rr) {
      if (mk[rr] != 0) {
        const float* t = f + rr * DD;
        acc[0] += 1.f;
#pragma unroll
        for (int k = 0; k < DD; ++k) acc[1 + k] += t[k];
        int u = 10;
#pragma unroll
        for (int p = 0; p < DD; ++p)
#pragma unroll
          for (int q = p; q < DD; ++q) acc[u++] += t[p] * t[q];
      }
    }
  }
#pragma unroll
  for (int k = 0; k < 55; ++k) {
    float v = acc[k];
#pragma unroll
    for (int off = 32; off > 0; off >>= 1) v += __shfl_down(v, off, 64);
    if ((tid & 63) == 0) part[tid >> 6][k] = v;
  }
  if (tid == 0) ws->ticket = 0u;  // kernel-boundary coherence covers dist's atomic
  __syncthreads();

  if (tid < 55) {
    double s = 0.0;
#pragma unroll
    for (int w = 0; w < 8; ++w) s += (double)part[w][tid];
    Sd[tid] = s;
  }
  __syncthreads();

  // ---- phase 2: fp64 Gauss-Jordan on wave 0 (lane p owns augmented row p)
  if (tid < 64) {
    const int lane = tid;
    const double cnt = Sd[0];
    const int p = (lane < DD) ? lane : 0;  // junk lanes mirror row 0
    double row[2 * DD];
    {
      const double mu_p = Sd[1 + p] / cnt;
#pragma unroll
      for (int q = 0; q < DD; ++q) {
        const int pp = (p < q) ? p : q;
        const int qq = (p < q) ? q : p;
        const int idx = 10 + 9 * pp - (pp * (pp - 1)) / 2 + (qq - pp);
        row[q] = (Sd[idx] - cnt * mu_p * (Sd[1 + q] / cnt)) / (cnt - 1.0);
        row[DD + q] = (p == q) ? 1.0 : 0.0;
      }
    }
#pragma unroll
    for (int c = 0; c < DD; ++c) {
      const double diag = __shfl(row[c], c, 64);
      const double dinv = 1.0 / diag;
      if (lane == c) {
#pragma unroll
        for (int q = 0; q < 2 * DD; ++q) row[q] *= dinv;
      }
      const double f = (lane == c) ? 0.0 : row[c];
#pragma unroll
      for (int q = 0; q < 2 * DD; ++q) {
        const double pv = __shfl(row[q], c, 64);
        row[q] -= f * pv;
      }
    }
    if (lane < DD) {
#pragma unroll
      for (int q = 0; q < DD; ++q) {
        const float cf = (float)row[DD + q];
        Cs[lane * DD + q] = cf;
        ws->cinv[lane * DD + q] = cf;
      }
    }
    if (lane == 0) {
      ws->cnt = (float)cnt;
#pragma unroll
      for (int q = 0; q < DD; ++q) ws->mean[q] = (float)(Sd[1 + q] / cnt);
    }
  }
  __syncthreads();

  // ---- phase 3: qy + SoA transpose, 8 consecutive j per thread
  {
    const int j0 = tid * 8;
    const int b = j0 >> 10;
    const int jj = j0 & (NN - 1);
    float C[DD * DD];
#pragma unroll
    for (int k = 0; k < DD * DD; ++k) C[k] = Cs[k];
    const float4* op4 = (const float4*)outputs + 18 * tid;
    float4 so4[18];
#pragma unroll
    for (int i = 0; i < 18; ++i) so4[i] = op4[i];
    const float* f = (const float*)so4;
#pragma unroll
    for (int g = 0; g < 2; ++g) {
      float qv[4];
#pragma unroll
      for (int rr = 0; rr < 4; ++rr) {
        const float* y = f + (g * 4 + rr) * DD;
        float qq = 0.f;
#pragma unroll
        for (int p = 0; p < DD; ++p) {
          float s = 0.f;
#pragma unroll
          for (int t = 0; t < DD; ++t) s += C[p * DD + t] * y[t];
          qq += y[p] * s;
        }
        qv[rr] = qq;
      }
#pragma unroll
      for (int p = 0; p < DD; ++p) {
        float4 o;
        o.x = f[(g * 4 + 0) * DD + p];
        o.y = f[(g * 4 + 1) * DD + p];
        o.z = f[(g * 4 + 2) * DD + p];
        o.w = f[(g * 4 + 3) * DD + p];
        *(float4*)(&ws->yT[(b * DD + p) * NN + jj + g * 4]) = o;
      }
      *(float4*)(&ws->qy[b * NN + jj + g * 4]) =
          make_float4(qv[0], qv[1], qv[2], qv[3]);
    }
  }
}

// ---------------------------------------------------------------------------
// Top-16-smallest sum over 1024 values (16/lane): per-lane bitonic sort +
// 6 shfl_xor half-cleaner rounds; re-merge skipped after the last round
// (half-cleaner output already holds exactly the top-16 multiset).
// ---------------------------------------------------------------------------
__device__ __forceinline__ float top16_sum(float (&v)[16]) {
#pragma unroll
  for (int k = 2; k <= 16; k <<= 1) {
#pragma unroll
    for (int j = k >> 1; j > 0; j >>= 1) {
#pragma unroll
      for (int i = 0; i < 16; ++i) {
        const int l = i ^ j;
        if (l > i) {
          const bool up = ((i & k) == 0);
          const float lo = fminf(v[i], v[l]);
          const float hi = fmaxf(v[i], v[l]);
          v[i] = up ? lo : hi;
          v[l] = up ? hi : lo;
        }
      }
    }
  }
#pragma unroll
  for (int off = 1; off < 64; off <<= 1) {
    float pr[16];
#pragma unroll
    for (int i = 0; i < 16; ++i) pr[i] = __shfl_xor(v[i], off, 64);
#pragma unroll
    for (int i = 0; i < 16; ++i) v[i] = fminf(v[i], pr[15 - i]);
    if (off < 32) {
#pragma unroll
      for (int j = 8; j > 0; j >>= 1) {
#pragma unroll
        for (int i = 0; i < 16; ++i) {
          const int l = i ^ j;
          if (l > i) {
            const float lo = fminf(v[i], v[l]);
            const float hi = fmaxf(v[i], v[l]);
            v[i] = lo;
            v[l] = hi;
          }
        }
      }
    }
  }
  float total = v[0];
#pragma unroll
  for (int k = 1; k < 16; ++k) total += v[k];
  return total;
}

// ---------------------------------------------------------------------------
// Kernel B: 1024 blocks x 256, NO min-waves hint (R1: the ",4" hint forced
// VGPR=64 and spilled 16.7MB to scratch). One wave per row r handles BOTH the
// intra row (if unmasked) and the outer row => each yT/qy plane load feeds
// two accumulator sets, halving L2 traffic vs one-row-per-wave. The two
// selection networks run sequentially to bound live registers. Last block
// (agent-scope ticket) folds in the finalize reduction; rowsum crosses XCDs
// via agent-scope atomics so non-coherent per-XCD L2s are bypassed.
// ---------------------------------------------------------------------------
__global__ __launch_bounds__(256) void dist_kernel(
    const float* __restrict__ outputs, const float* __restrict__ targets,
    const int* __restrict__ mask, Ws* __restrict__ ws,
    float* __restrict__ out) {
  const int tid = threadIdx.x;
  const int wv = tid >> 6;
  const int lane = tid & 63;
  const int r = blockIdx.x * 4 + wv;  // 0..4095
  const int b = r >> 10;
  const bool live = (mask[r] != 0);   // wave-uniform

  // outer side: u = y_r + mean (reference subtracts mean from the DIFF)
  float wo[DD];
  float qa_o = 0.f;
  {
    float ao[DD];
#pragma unroll
    for (int k = 0; k < DD; ++k) ao[k] = outputs[r * DD + k] + ws->mean[k];
#pragma unroll
    for (int p = 0; p < DD; ++p) {
      float s = 0.f;
#pragma unroll
      for (int t = 0; t < DD; ++t) s += ws->cinv[p * DD + t] * ao[t];
      wo[p] = s;
      qa_o += ao[p] * s;
    }
  }
  // intra side: a = t_r - mean
  float wi[DD];
  float qa_i = 0.f;
  if (live) {
    float ai[DD];
#pragma unroll
    for (int k = 0; k < DD; ++k) ai[k] = targets[r * DD + k] - ws->mean[k];
#pragma unroll
    for (int p = 0; p < DD; ++p) {
      float s = 0.f;
#pragma unroll
      for (int t = 0; t < DD; ++t) s += ws->cinv[p * DD + t] * ai[t];
      wi[p] = s;
      qa_i += ai[p] * s;
    }
  }

  float vi[16], vo[16];
#pragma unroll
  for (int k = 0; k < 16; ++k) {
    vi[k] = 0.f;
    vo[k] = 0.f;
  }
  const float* __restrict__ yTb = ws->yT + (size_t)b * DD * NN;
  if (live) {
#pragma unroll
    for (int p = 0; p < DD; ++p) {
      const float4* __restrict__ pl = (const float4*)(yTb + (size_t)p * NN);
#pragma unroll
      for (int c = 0; c < 4; ++c) {
        const float4 y4 = pl[c * 64 + lane];
        vi[c * 4 + 0] += wi[p] * y4.x;
        vi[c * 4 + 1] += wi[p] * y4.y;
        vi[c * 4 + 2] += wi[p] * y4.z;
        vi[c * 4 + 3] += wi[p] * y4.w;
        vo[c * 4 + 0] += wo[p] * y4.x;
        vo[c * 4 + 1] += wo[p] * y4.y;
        vo[c * 4 + 2] += wo[p] * y4.z;
        vo[c * 4 + 3] += wo[p] * y4.w;
      }
    }
  } else {
#pragma unroll
    for (int p = 0; p < DD; ++p) {
      const float4* __restrict__ pl = (const float4*)(yTb + (size_t)p * NN);
#pragma unroll
      for (int c = 0; c < 4; ++c) {
        const float4 y4 = pl[c * 64 + lane];
        vo[c * 4 + 0] += wo[p] * y4.x;
        vo[c * 4 + 1] += wo[p] * y4.y;
        vo[c * 4 + 2] += wo[p] * y4.z;
        vo[c * 4 + 3] += wo[p] * y4.w;
      }
    }
  }
  {
    const float4* __restrict__ q4 = (const float4*)(ws->qy + (size_t)b * NN);
#pragma unroll
    for (int c = 0; c < 4; ++c) {
      const float4 qv = q4[c * 64 + lane];
      vo[c * 4 + 0] = qa_o + qv.x - 2.f * vo[c * 4 + 0];
      vo[c * 4 + 1] = qa_o + qv.y - 2.f * vo[c * 4 + 1];
      vo[c * 4 + 2] = qa_o + qv.z - 2.f * vo[c * 4 + 2];
      vo[c * 4 + 3] = qa_o + qv.w - 2.f * vo[c * 4 + 3];
      if (live) {
        vi[c * 4 + 0] = qa_i + qv.x - 2.f * vi[c * 4 + 0];
        vi[c * 4 + 1] = qa_i + qv.y - 2.f * vi[c * 4 + 1];
        vi[c * 4 + 2] = qa_i + qv.z - 2.f * vi[c * 4 + 2];
        vi[c * 4 + 3] = qa_i + qv.w - 2.f * vi[c * 4 + 3];
      }
    }
  }

  float si = 0.f;
  if (live) si = top16_sum(vi);
  const float so = top16_sum(vo);
  if (lane == 0) {
    __hip_atomic_store(&ws->rowsum[r], si, __ATOMIC_RELAXED,
                       __HIP_MEMORY_SCOPE_AGENT);
    __hip_atomic_store(&ws->rowsum[NROW + r], so, __ATOMIC_RELAXED,
                       __HIP_MEMORY_SCOPE_AGENT);
  }

  // ---- last-block finalize (syncthreads drains vmcnt => stores visible)
  __syncthreads();
  __shared__ int slast;
  if (tid == 0) {
    const unsigned int old = __hip_atomic_fetch_add(
        &ws->ticket, 1u, __ATOMIC_ACQ_REL, __HIP_MEMORY_SCOPE_AGENT);
    slast = (old == (unsigned int)(gridDim.x - 1)) ? 1 : 0;
  }
  __syncthreads();
  if (slast != 0) {
    double li = 0.0, lo = 0.0;
    for (int k = tid; k < NROW; k += 256) {
      li += (double)__hip_atomic_load(&ws->rowsum[k], __ATOMIC_RELAXED,
                                      __HIP_MEMORY_SCOPE_AGENT);
      lo += (double)__hip_atomic_load(&ws->rowsum[NROW + k], __ATOMIC_RELAXED,
                                      __HIP_MEMORY_SCOPE_AGENT);
    }
#pragma unroll
    for (int off = 32; off > 0; off >>= 1) {
      li += __shfl_down(li, off, 64);
      lo += __shfl_down(lo, off, 64);
    }
    __shared__ double lds_i[4], lds_o[4];
    if ((tid & 63) == 0) {
      lds_i[tid >> 6] = li;
      lds_o[tid >> 6] = lo;
    }
    __syncthreads();
    if (tid == 0) {
      const double sI = lds_i[0] + lds_i[1] + lds_i[2] + lds_i[3];
      const double sO = lds_o[0] + lds_o[1] + lds_o[2] + lds_o[3];
      const float intra = (float)(sI / (double)ws->cnt);
      const float outer = (float)(sO / (double)(NROW * KSEL));
      out[0] = intra;
      out[1] = intra;
      out[2] = outer;
    }
  }
}

extern "C" void kernel_launch(void* const* d_in, const int* in_sizes, int n_in,
                              void* d_out, int out_size, void* d_ws,
                              size_t ws_size, hipStream_t stream) {
  const float* outputs = (const float*)d_in[0];  // (4,1024,9) f32
  const float* targets = (const float*)d_in[1];  // (4,1024,9) f32
  const int* mask = (const int*)d_in[2];         // (4,1024) int32
  Ws* ws = (Ws*)d_ws;
  float* out = (float*)d_out;

  setup_kernel<<<1, 512, 0, stream>>>(outputs, targets, mask, ws);
  dist_kernel<<<NROW / 4, 256, 0, stream>>>(outputs, targets, mask, ws, out);
}

// Round 3
// 107.886 us; speedup vs baseline: 1.1622x; 1.1071x over previous
//
#include <hip/hip_runtime.h>
#include <math.h>

#define BB   4
#define MM   1024
#define NN   1024
#define DD   9
#define KSEL 16
#define NROW (BB * MM)        // 4096 rows; wave r handles intra-row r AND outer-row r
#define NSLOT (2 * NROW)

// Workspace. yT first => 16B-aligned float4 planes. Every field written before
// read each launch. Harness re-poisons the full d_ws (2 x ~39us fills) inside
// the timed window: ~78us session floor we cannot touch.
// R1 lesson: __launch_bounds__(256,4) -> VGPR=64 -> 16.7MB scratch spill.
// R2 lesson: spill fixed but dist stayed 41us at 16% occupancy -> the fused
// ticket finalize (1024 serialized acq_rel atomics + agent-scope loads on a
// near-empty GPU) was the real tail. This round: separate 1-block finalize,
// plain memory ops, and ONE selection network (looped over sides, not
// duplicated) to halve dist's straight-line code.
struct Ws {
  float yT[BB * DD * NN];     // [b][p][j] SoA planes
  float qy[BB * NN];          // y_j^T Cinv y_j
  float rowsum[NSLOT];        // [0,4096): intra sums; [4096,8192): outer sums
  float cnt;
  float mean[DD];
  float cinv[DD * DD];
};

// ---------------------------------------------------------------------------
// Kernel A: ONE block x 512. Phase 1: masked moment partials (8 rows/thread,
// float4-staged). Phase 2: wave 0 fp64 Gauss-Jordan (cov of ~2048 N(0,1)
// samples is SPD, diag~1 => no pivoting needed, pinv == inverse). Phase 3:
// SoA transpose + qy for all 4096 outputs (8 consecutive j/thread, float4
// loads AND stores). Single block => only __syncthreads, no cross-block sync.
// ---------------------------------------------------------------------------
__global__ __launch_bounds__(512) void setup_kernel(
    const float* __restrict__ outputs, const float* __restrict__ targets,
    const int* __restrict__ mask, Ws* __restrict__ ws) {
  const int tid = threadIdx.x;  // 0..511
  __shared__ float part[8][55];
  __shared__ double Sd[55];
  __shared__ float Cs[DD * DD];

  // ---- phase 1: moments over rows 8t..8t+7 (72 floats = 18 float4, exact)
  float acc[55];
#pragma unroll
  for (int k = 0; k < 55; ++k) acc[k] = 0.f;
  {
    const float4* tp = (const float4*)targets + 18 * tid;
    float4 st4[18];
#pragma unroll
    for (int i = 0; i < 18; ++i) st4[i] = tp[i];
    const float* f = (const float*)st4;
    const int4 m0 = ((const int4*)mask)[2 * tid];
    const int4 m1 = ((const int4*)mask)[2 * tid + 1];
    const int mk[8] = {m0.x, m0.y, m0.z, m0.w, m1.x, m1.y, m1.z, m1.w};
#pragma unroll
    for (int rr = 0; rr < 8; ++rr) {
      if (mk[rr] != 0) {
        const float* t = f + rr * DD;
        acc[0] += 1.f;
#pragma unroll
        for (int k = 0; k < DD; ++k) acc[1 + k] += t[k];
        int u = 10;
#pragma unroll
        for (int p = 0; p < DD; ++p)
#pragma unroll
          for (int q = p; q < DD; ++q) acc[u++] += t[p] * t[q];
      }
    }
  }
#pragma unroll
  for (int k = 0; k < 55; ++k) {
    float v = acc[k];
#pragma unroll
    for (int off = 32; off > 0; off >>= 1) v += __shfl_down(v, off, 64);
    if ((tid & 63) == 0) part[tid >> 6][k] = v;
  }
  __syncthreads();

  if (tid < 55) {
    double s = 0.0;
#pragma unroll
    for (int w = 0; w < 8; ++w) s += (double)part[w][tid];
    Sd[tid] = s;
  }
  __syncthreads();

  // ---- phase 2: fp64 Gauss-Jordan on wave 0 (lane p owns augmented row p)
  if (tid < 64) {
    const int lane = tid;
    const double cnt = Sd[0];
    const int p = (lane < DD) ? lane : 0;  // junk lanes mirror row 0
    double row[2 * DD];
    {
      const double mu_p = Sd[1 + p] / cnt;
#pragma unroll
      for (int q = 0; q < DD; ++q) {
        const int pp = (p < q) ? p : q;
        const int qq = (p < q) ? q : p;
        const int idx = 10 + 9 * pp - (pp * (pp - 1)) / 2 + (qq - pp);
        row[q] = (Sd[idx] - cnt * mu_p * (Sd[1 + q] / cnt)) / (cnt - 1.0);
        row[DD + q] = (p == q) ? 1.0 : 0.0;
      }
    }
#pragma unroll
    for (int c = 0; c < DD; ++c) {
      const double diag = __shfl(row[c], c, 64);
      const double dinv = 1.0 / diag;
      if (lane == c) {
#pragma unroll
        for (int q = 0; q < 2 * DD; ++q) row[q] *= dinv;
      }
      const double f = (lane == c) ? 0.0 : row[c];
#pragma unroll
      for (int q = 0; q < 2 * DD; ++q) {
        const double pv = __shfl(row[q], c, 64);
        row[q] -= f * pv;
      }
    }
    if (lane < DD) {
#pragma unroll
      for (int q = 0; q < DD; ++q) {
        const float cf = (float)row[DD + q];
        Cs[lane * DD + q] = cf;
        ws->cinv[lane * DD + q] = cf;
      }
    }
    if (lane == 0) {
      ws->cnt = (float)cnt;
#pragma unroll
      for (int q = 0; q < DD; ++q) ws->mean[q] = (float)(Sd[1 + q] / cnt);
    }
  }
  __syncthreads();

  // ---- phase 3: qy + SoA transpose, 8 consecutive j per thread
  {
    const int j0 = tid * 8;
    const int b = j0 >> 10;
    const int jj = j0 & (NN - 1);
    float C[DD * DD];
#pragma unroll
    for (int k = 0; k < DD * DD; ++k) C[k] = Cs[k];
    const float4* op4 = (const float4*)outputs + 18 * tid;
    float4 so4[18];
#pragma unroll
    for (int i = 0; i < 18; ++i) so4[i] = op4[i];
    const float* f = (const float*)so4;
#pragma unroll
    for (int g = 0; g < 2; ++g) {
      float qv[4];
#pragma unroll
      for (int rr = 0; rr < 4; ++rr) {
        const float* y = f + (g * 4 + rr) * DD;
        float qq = 0.f;
#pragma unroll
        for (int p = 0; p < DD; ++p) {
          float s = 0.f;
#pragma unroll
          for (int t = 0; t < DD; ++t) s += C[p * DD + t] * y[t];
          qq += y[p] * s;
        }
        qv[rr] = qq;
      }
#pragma unroll
      for (int p = 0; p < DD; ++p) {
        float4 o;
        o.x = f[(g * 4 + 0) * DD + p];
        o.y = f[(g * 4 + 1) * DD + p];
        o.z = f[(g * 4 + 2) * DD + p];
        o.w = f[(g * 4 + 3) * DD + p];
        *(float4*)(&ws->yT[(b * DD + p) * NN + jj + g * 4]) = o;
      }
      *(float4*)(&ws->qy[b * NN + jj + g * 4]) =
          make_float4(qv[0], qv[1], qv[2], qv[3]);
    }
  }
}

// ---------------------------------------------------------------------------
// Kernel B: 1024 blocks x 256, uncapped VGPRs. One wave per row r handles
// BOTH the intra row (if unmasked) and the outer row: a single pass over the
// yT/qy planes feeds both accumulator sets (half the L2 traffic of one-row-
// per-wave). The top-16 selection network exists ONCE, in a no-unroll loop
// over sides (v copied from vi/vo via cndmask - static indices, registers).
// Dead waves start the loop at s=1 (outer only). Plain stores; coherence via
// kernel boundary. No atomics, no tail.
// ---------------------------------------------------------------------------
__global__ __launch_bounds__(256) void dist_kernel(
    const float* __restrict__ outputs, const float* __restrict__ targets,
    const int* __restrict__ mask, Ws* __restrict__ ws) {
  const int tid = threadIdx.x;
  const int wv = tid >> 6;
  const int lane = tid & 63;
  const int r = blockIdx.x * 4 + wv;  // 0..4095
  const int b = r >> 10;
  const bool live = (mask[r] != 0);   // wave-uniform

  // outer side: u = y_r + mean (reference subtracts mean from the DIFF);
  // intra side: a = t_r - mean. Both rows are valid memory regardless of
  // mask (targets are all finite), so compute both unconditionally - one
  // straight-line code path.
  float wo[DD], wi[DD];
  float qa_o = 0.f, qa_i = 0.f;
  {
    float ao[DD], ai[DD];
#pragma unroll
    for (int k = 0; k < DD; ++k) {
      const float mk = ws->mean[k];
      ao[k] = outputs[r * DD + k] + mk;
      ai[k] = targets[r * DD + k] - mk;
    }
#pragma unroll
    for (int p = 0; p < DD; ++p) {
      float so = 0.f, si = 0.f;
#pragma unroll
      for (int t = 0; t < DD; ++t) {
        const float cv = ws->cinv[p * DD + t];
        so += cv * ao[t];
        si += cv * ai[t];
      }
      wo[p] = so;
      qa_o += ao[p] * so;
      wi[p] = si;
      qa_i += ai[p] * si;
    }
  }

  float vi[16], vo[16];
#pragma unroll
  for (int k = 0; k < 16; ++k) {
    vi[k] = 0.f;
    vo[k] = 0.f;
  }
  const float* __restrict__ yTb = ws->yT + (size_t)b * DD * NN;
#pragma unroll
  for (int p = 0; p < DD; ++p) {
    const float4* __restrict__ pl = (const float4*)(yTb + (size_t)p * NN);
#pragma unroll
    for (int c = 0; c < 4; ++c) {
      const float4 y4 = pl[c * 64 + lane];
      vi[c * 4 + 0] += wi[p] * y4.x;
      vi[c * 4 + 1] += wi[p] * y4.y;
      vi[c * 4 + 2] += wi[p] * y4.z;
      vi[c * 4 + 3] += wi[p] * y4.w;
      vo[c * 4 + 0] += wo[p] * y4.x;
      vo[c * 4 + 1] += wo[p] * y4.y;
      vo[c * 4 + 2] += wo[p] * y4.z;
      vo[c * 4 + 3] += wo[p] * y4.w;
    }
  }
  {
    const float4* __restrict__ q4 = (const float4*)(ws->qy + (size_t)b * NN);
#pragma unroll
    for (int c = 0; c < 4; ++c) {
      const float4 qv = q4[c * 64 + lane];
      vi[c * 4 + 0] = qa_i + qv.x - 2.f * vi[c * 4 + 0];
      vi[c * 4 + 1] = qa_i + qv.y - 2.f * vi[c * 4 + 1];
      vi[c * 4 + 2] = qa_i + qv.z - 2.f * vi[c * 4 + 2];
      vi[c * 4 + 3] = qa_i + qv.w - 2.f * vi[c * 4 + 3];
      vo[c * 4 + 0] = qa_o + qv.x - 2.f * vo[c * 4 + 0];
      vo[c * 4 + 1] = qa_o + qv.y - 2.f * vo[c * 4 + 1];
      vo[c * 4 + 2] = qa_o + qv.z - 2.f * vo[c * 4 + 2];
      vo[c * 4 + 3] = qa_o + qv.w - 2.f * vo[c * 4 + 3];
    }
  }

  // ---- top-16 selection: ONE network instance, looped over sides.
  // Per-lane bitonic sort + 6 shfl_xor half-cleaner rounds; re-merge after
  // the last round skipped (half-cleaner output already holds the top-16
  // multiset). Dead waves (live==0) run only s=1 (outer).
  float si_sum = 0.f, so_sum = 0.f;
#pragma unroll 1
  for (int s = live ? 0 : 1; s < 2; ++s) {
    float v[16];
#pragma unroll
    for (int i = 0; i < 16; ++i) v[i] = (s == 0) ? vi[i] : vo[i];

#pragma unroll
    for (int k = 2; k <= 16; k <<= 1) {
#pragma unroll
      for (int j = k >> 1; j > 0; j >>= 1) {
#pragma unroll
        for (int i = 0; i < 16; ++i) {
          const int l = i ^ j;
          if (l > i) {
            const bool up = ((i & k) == 0);
            const float lo = fminf(v[i], v[l]);
            const float hi = fmaxf(v[i], v[l]);
            v[i] = up ? lo : hi;
            v[l] = up ? hi : lo;
          }
        }
      }
    }
#pragma unroll
    for (int off = 1; off < 64; off <<= 1) {
      float pr[16];
#pragma unroll
      for (int i = 0; i < 16; ++i) pr[i] = __shfl_xor(v[i], off, 64);
#pragma unroll
      for (int i = 0; i < 16; ++i) v[i] = fminf(v[i], pr[15 - i]);
      if (off < 32) {
#pragma unroll
        for (int j = 8; j > 0; j >>= 1) {
#pragma unroll
          for (int i = 0; i < 16; ++i) {
            const int l = i ^ j;
            if (l > i) {
              const float lo = fminf(v[i], v[l]);
              const float hi = fmaxf(v[i], v[l]);
              v[i] = lo;
              v[l] = hi;
            }
          }
        }
      }
    }
    float total = v[0];
#pragma unroll
    for (int k = 1; k < 16; ++k) total += v[k];
    if (s == 0) si_sum = total;
    else so_sum = total;
  }

  if (lane == 0) {
    ws->rowsum[r] = si_sum;          // 0 for dead waves (never computed)
    ws->rowsum[NROW + r] = so_sum;
  }
}

// ---------------------------------------------------------------------------
// Kernel C: one block; reduce 8192 row sums -> three scalars. Plain loads
// (kernel-boundary coherence; rowsum is warm in cache).
// ---------------------------------------------------------------------------
__global__ __launch_bounds__(256) void finalize_kernel(
    const Ws* __restrict__ ws, float* __restrict__ out) {
  const int tid = threadIdx.x;
  double li = 0.0, lo = 0.0;
  for (int k = tid; k < NROW; k += 256) {
    li += (double)ws->rowsum[k];
    lo += (double)ws->rowsum[NROW + k];
  }
#pragma unroll
  for (int off = 32; off > 0; off >>= 1) {
    li += __shfl_down(li, off, 64);
    lo += __shfl_down(lo, off, 64);
  }
  __shared__ double lds_i[4], lds_o[4];
  if ((tid & 63) == 0) {
    lds_i[tid >> 6] = li;
    lds_o[tid >> 6] = lo;
  }
  __syncthreads();
  if (tid == 0) {
    const double sI = lds_i[0] + lds_i[1] + lds_i[2] + lds_i[3];
    const double sO = lds_o[0] + lds_o[1] + lds_o[2] + lds_o[3];
    const float intra = (float)(sI / (double)ws->cnt);
    const float outer = (float)(sO / (double)(NROW * KSEL));
    out[0] = intra;
    out[1] = intra;
    out[2] = outer;
  }
}

extern "C" void kernel_launch(void* const* d_in, const int* in_sizes, int n_in,
                              void* d_out, int out_size, void* d_ws,
                              size_t ws_size, hipStream_t stream) {
  const float* outputs = (const float*)d_in[0];  // (4,1024,9) f32
  const float* targets = (const float*)d_in[1];  // (4,1024,9) f32
  const int* mask = (const int*)d_in[2];         // (4,1024) int32
  Ws* ws = (Ws*)d_ws;
  float* out = (float*)d_out;

  setup_kernel<<<1, 512, 0, stream>>>(outputs, targets, mask, ws);
  dist_kernel<<<NROW / 4, 256, 0, stream>>>(outputs, targets, mask, ws);
  finalize_kernel<<<1, 256, 0, stream>>>(ws, out);
}

// Round 4
// 98.994 us; speedup vs baseline: 1.2665x; 1.0898x over previous
//
#include <hip/hip_runtime.h>
#include <math.h>

#define BB   4
#define MM   1024
#define NN   1024
#define DD   9
#define KSEL 16
#define NROW (BB * MM)        // 4096 rows; wave r handles intra-row r AND outer-row r
#define NSLOT (2 * NROW)

// Workspace. yT first => 16B-aligned float4 planes. Every field written before
// read each launch. Harness re-poisons the full d_ws (2 x ~39.3us fills)
// inside the timed window: ~78.6us session floor we cannot touch.
// R1: __launch_bounds__(256,4) -> VGPR=64 -> 16.7MB scratch spill (46us dist).
// R2: ticket finalize (1024 serialized acq_rel atomics) + 2x inlined
//     selection networks -> 41us dist at 16% occupancy.
// R3: dist fixed (<39us, off top-5) but ONE-block setup = ~19us serial tail
//     on a single CU (300KB + all moments, 2 waves/SIMD).
// R4: setup re-parallelized: 8 blocks x 512, moments+GJ computed REDUNDANTLY
//     per block (cheap, deterministic, no cross-block sync), transpose/qy
//     spread over all 4096 threads. dist/finalize unchanged from R3.
struct Ws {
  float yT[BB * DD * NN];     // [b][p][j] SoA planes
  float qy[BB * NN];          // y_j^T Cinv y_j
  float rowsum[NSLOT];        // [0,4096): intra sums; [4096,8192): outer sums
  float cnt;
  float mean[DD];
  float cinv[DD * DD];
};

// ---------------------------------------------------------------------------
// Kernel A: 8 blocks x 512. Phase 1: EVERY block computes the full masked
// moment partials (8 consecutive rows/thread, float4-staged - identical
// arithmetic order to the R3-verified version). Phase 2: wave 0 fp64
// Gauss-Jordan (cov of ~2048 N(0,1) samples is SPD, diag~1 => no pivoting,
// pinv == inverse); all blocks derive the identical Cs; block 0 publishes.
// Phase 3: qy + SoA transpose, ONE output per thread (j = blk*512+tid),
// coalesced plane stores. Redundant phases 1-2 cost ~1us/block on separate
// CUs - far cheaper than a launch gap + global partial round-trip.
// ---------------------------------------------------------------------------
__global__ __launch_bounds__(512) void prep_kernel(
    const float* __restrict__ outputs, const float* __restrict__ targets,
    const int* __restrict__ mask, Ws* __restrict__ ws) {
  const int tid = threadIdx.x;  // 0..511
  __shared__ float part[8][55];
  __shared__ double Sd[55];
  __shared__ float Cs[DD * DD];

  // ---- phase 1: moments over rows 8t..8t+7 (72 floats = 18 float4, exact)
  float acc[55];
#pragma unroll
  for (int k = 0; k < 55; ++k) acc[k] = 0.f;
  {
    const float4* tp = (const float4*)targets + 18 * tid;
    float4 st4[18];
#pragma unroll
    for (int i = 0; i < 18; ++i) st4[i] = tp[i];
    const float* f = (const float*)st4;
    const int4 m0 = ((const int4*)mask)[2 * tid];
    const int4 m1 = ((const int4*)mask)[2 * tid + 1];
    const int mk[8] = {m0.x, m0.y, m0.z, m0.w, m1.x, m1.y, m1.z, m1.w};
#pragma unroll
    for (int rr = 0; rr < 8; ++rr) {
      if (mk[rr] != 0) {
        const float* t = f + rr * DD;
        acc[0] += 1.f;
#pragma unroll
        for (int k = 0; k < DD; ++k) acc[1 + k] += t[k];
        int u = 10;
#pragma unroll
        for (int p = 0; p < DD; ++p)
#pragma unroll
          for (int q = p; q < DD; ++q) acc[u++] += t[p] * t[q];
      }
    }
  }
#pragma unroll
  for (int k = 0; k < 55; ++k) {
    float v = acc[k];
#pragma unroll
    for (int off = 32; off > 0; off >>= 1) v += __shfl_down(v, off, 64);
    if ((tid & 63) == 0) part[tid >> 6][k] = v;
  }
  __syncthreads();

  if (tid < 55) {
    double s = 0.0;
#pragma unroll
    for (int w = 0; w < 8; ++w) s += (double)part[w][tid];
    Sd[tid] = s;
  }
  __syncthreads();

  // ---- phase 2: fp64 Gauss-Jordan on wave 0 (lane p owns augmented row p)
  if (tid < 64) {
    const int lane = tid;
    const double cnt = Sd[0];
    const int p = (lane < DD) ? lane : 0;  // junk lanes mirror row 0
    double row[2 * DD];
    {
      const double mu_p = Sd[1 + p] / cnt;
#pragma unroll
      for (int q = 0; q < DD; ++q) {
        const int pp = (p < q) ? p : q;
        const int qq = (p < q) ? q : p;
        const int idx = 10 + 9 * pp - (pp * (pp - 1)) / 2 + (qq - pp);
        row[q] = (Sd[idx] - cnt * mu_p * (Sd[1 + q] / cnt)) / (cnt - 1.0);
        row[DD + q] = (p == q) ? 1.0 : 0.0;
      }
    }
#pragma unroll
    for (int c = 0; c < DD; ++c) {
      const double diag = __shfl(row[c], c, 64);
      const double dinv = 1.0 / diag;
      if (lane == c) {
#pragma unroll
        for (int q = 0; q < 2 * DD; ++q) row[q] *= dinv;
      }
      const double f = (lane == c) ? 0.0 : row[c];
#pragma unroll
      for (int q = 0; q < 2 * DD; ++q) {
        const double pv = __shfl(row[q], c, 64);
        row[q] -= f * pv;
      }
    }
    if (lane < DD) {
#pragma unroll
      for (int q = 0; q < DD; ++q) {
        const float cf = (float)row[DD + q];
        Cs[lane * DD + q] = cf;
        if (blockIdx.x == 0) ws->cinv[lane * DD + q] = cf;
      }
    }
    if (lane == 0 && blockIdx.x == 0) {
      ws->cnt = (float)cnt;
#pragma unroll
      for (int q = 0; q < DD; ++q) ws->mean[q] = (float)(Sd[1 + q] / cnt);
    }
  }
  __syncthreads();

  // ---- phase 3: qy + SoA transpose, ONE output per thread (coalesced)
  {
    const int j = (blockIdx.x << 9) + tid;  // 0..4095
    const int b = j >> 10;
    const int jj = j & (NN - 1);
    float C[DD * DD];
#pragma unroll
    for (int k = 0; k < DD * DD; ++k) C[k] = Cs[k];
    float y[DD];
#pragma unroll
    for (int k = 0; k < DD; ++k) y[k] = outputs[j * DD + k];
    float q = 0.f;
#pragma unroll
    for (int p = 0; p < DD; ++p) {
      float s = 0.f;
#pragma unroll
      for (int t = 0; t < DD; ++t) s += C[p * DD + t] * y[t];
      q += y[p] * s;
      ws->yT[(b * DD + p) * NN + jj] = y[p];
    }
    ws->qy[j] = q;
  }
}

// ---------------------------------------------------------------------------
// Kernel B: 1024 blocks x 256, uncapped VGPRs (R1 lesson). One wave per row r
// handles BOTH the intra row (if unmasked) and the outer row: a single pass
// over the yT/qy planes feeds both accumulator sets (half the L2 traffic of
// one-row-per-wave). The top-16 selection network exists ONCE, in a no-unroll
// loop over sides (R2 lesson: duplicating it doubled straight-line code).
// Dead waves start the loop at s=1 (outer only). Plain stores; coherence via
// kernel boundary. No atomics, no tail. [R3-verified]
// ---------------------------------------------------------------------------
__global__ __launch_bounds__(256) void dist_kernel(
    const float* __restrict__ outputs, const float* __restrict__ targets,
    const int* __restrict__ mask, Ws* __restrict__ ws) {
  const int tid = threadIdx.x;
  const int wv = tid >> 6;
  const int lane = tid & 63;
  const int r = blockIdx.x * 4 + wv;  // 0..4095
  const int b = r >> 10;
  const bool live = (mask[r] != 0);   // wave-uniform

  // outer side: u = y_r + mean (reference subtracts mean from the DIFF);
  // intra side: a = t_r - mean. Both computed unconditionally - one
  // straight-line code path.
  float wo[DD], wi[DD];
  float qa_o = 0.f, qa_i = 0.f;
  {
    float ao[DD], ai[DD];
#pragma unroll
    for (int k = 0; k < DD; ++k) {
      const float mk = ws->mean[k];
      ao[k] = outputs[r * DD + k] + mk;
      ai[k] = targets[r * DD + k] - mk;
    }
#pragma unroll
    for (int p = 0; p < DD; ++p) {
      float so = 0.f, si = 0.f;
#pragma unroll
      for (int t = 0; t < DD; ++t) {
        const float cv = ws->cinv[p * DD + t];
        so += cv * ao[t];
        si += cv * ai[t];
      }
      wo[p] = so;
      qa_o += ao[p] * so;
      wi[p] = si;
      qa_i += ai[p] * si;
    }
  }

  float vi[16], vo[16];
#pragma unroll
  for (int k = 0; k < 16; ++k) {
    vi[k] = 0.f;
    vo[k] = 0.f;
  }
  const float* __restrict__ yTb = ws->yT + (size_t)b * DD * NN;
#pragma unroll
  for (int p = 0; p < DD; ++p) {
    const float4* __restrict__ pl = (const float4*)(yTb + (size_t)p * NN);
#pragma unroll
    for (int c = 0; c < 4; ++c) {
      const float4 y4 = pl[c * 64 + lane];
      vi[c * 4 + 0] += wi[p] * y4.x;
      vi[c * 4 + 1] += wi[p] * y4.y;
      vi[c * 4 + 2] += wi[p] * y4.z;
      vi[c * 4 + 3] += wi[p] * y4.w;
      vo[c * 4 + 0] += wo[p] * y4.x;
      vo[c * 4 + 1] += wo[p] * y4.y;
      vo[c * 4 + 2] += wo[p] * y4.z;
      vo[c * 4 + 3] += wo[p] * y4.w;
    }
  }
  {
    const float4* __restrict__ q4 = (const float4*)(ws->qy + (size_t)b * NN);
#pragma unroll
    for (int c = 0; c < 4; ++c) {
      const float4 qv = q4[c * 64 + lane];
      vi[c * 4 + 0] = qa_i + qv.x - 2.f * vi[c * 4 + 0];
      vi[c * 4 + 1] = qa_i + qv.y - 2.f * vi[c * 4 + 1];
      vi[c * 4 + 2] = qa_i + qv.z - 2.f * vi[c * 4 + 2];
      vi[c * 4 + 3] = qa_i + qv.w - 2.f * vi[c * 4 + 3];
      vo[c * 4 + 0] = qa_o + qv.x - 2.f * vo[c * 4 + 0];
      vo[c * 4 + 1] = qa_o + qv.y - 2.f * vo[c * 4 + 1];
      vo[c * 4 + 2] = qa_o + qv.z - 2.f * vo[c * 4 + 2];
      vo[c * 4 + 3] = qa_o + qv.w - 2.f * vo[c * 4 + 3];
    }
  }

  // ---- top-16 selection: ONE network instance, looped over sides.
  // Per-lane bitonic sort + 6 shfl_xor half-cleaner rounds; re-merge after
  // the last round skipped (half-cleaner output already holds the top-16
  // multiset). Dead waves (live==0) run only s=1 (outer).
  float si_sum = 0.f, so_sum = 0.f;
#pragma unroll 1
  for (int s = live ? 0 : 1; s < 2; ++s) {
    float v[16];
#pragma unroll
    for (int i = 0; i < 16; ++i) v[i] = (s == 0) ? vi[i] : vo[i];

#pragma unroll
    for (int k = 2; k <= 16; k <<= 1) {
#pragma unroll
      for (int j = k >> 1; j > 0; j >>= 1) {
#pragma unroll
        for (int i = 0; i < 16; ++i) {
          const int l = i ^ j;
          if (l > i) {
            const bool up = ((i & k) == 0);
            const float lo = fminf(v[i], v[l]);
            const float hi = fmaxf(v[i], v[l]);
            v[i] = up ? lo : hi;
            v[l] = up ? hi : lo;
          }
        }
      }
    }
#pragma unroll
    for (int off = 1; off < 64; off <<= 1) {
      float pr[16];
#pragma unroll
      for (int i = 0; i < 16; ++i) pr[i] = __shfl_xor(v[i], off, 64);
#pragma unroll
      for (int i = 0; i < 16; ++i) v[i] = fminf(v[i], pr[15 - i]);
      if (off < 32) {
#pragma unroll
        for (int j = 8; j > 0; j >>= 1) {
#pragma unroll
          for (int i = 0; i < 16; ++i) {
            const int l = i ^ j;
            if (l > i) {
              const float lo = fminf(v[i], v[l]);
              const float hi = fmaxf(v[i], v[l]);
              v[i] = lo;
              v[l] = hi;
            }
          }
        }
      }
    }
    float total = v[0];
#pragma unroll
    for (int k = 1; k < 16; ++k) total += v[k];
    if (s == 0) si_sum = total;
    else so_sum = total;
  }

  if (lane == 0) {
    ws->rowsum[r] = si_sum;          // 0 for dead waves (never computed)
    ws->rowsum[NROW + r] = so_sum;
  }
}

// ---------------------------------------------------------------------------
// Kernel C: one block; reduce 8192 row sums -> three scalars. Plain loads
// (kernel-boundary coherence; rowsum is warm in cache).
// ---------------------------------------------------------------------------
__global__ __launch_bounds__(256) void finalize_kernel(
    const Ws* __restrict__ ws, float* __restrict__ out) {
  const int tid = threadIdx.x;
  double li = 0.0, lo = 0.0;
  for (int k = tid; k < NROW; k += 256) {
    li += (double)ws->rowsum[k];
    lo += (double)ws->rowsum[NROW + k];
  }
#pragma unroll
  for (int off = 32; off > 0; off >>= 1) {
    li += __shfl_down(li, off, 64);
    lo += __shfl_down(lo, off, 64);
  }
  __shared__ double lds_i[4], lds_o[4];
  if ((tid & 63) == 0) {
    lds_i[tid >> 6] = li;
    lds_o[tid >> 6] = lo;
  }
  __syncthreads();
  if (tid == 0) {
    const double sI = lds_i[0] + lds_i[1] + lds_i[2] + lds_i[3];
    const double sO = lds_o[0] + lds_o[1] + lds_o[2] + lds_o[3];
    const float intra = (float)(sI / (double)ws->cnt);
    const float outer = (float)(sO / (double)(NROW * KSEL));
    out[0] = intra;
    out[1] = intra;
    out[2] = outer;
  }
}

extern "C" void kernel_launch(void* const* d_in, const int* in_sizes, int n_in,
                              void* d_out, int out_size, void* d_ws,
                              size_t ws_size, hipStream_t stream) {
  const float* outputs = (const float*)d_in[0];  // (4,1024,9) f32
  const float* targets = (const float*)d_in[1];  // (4,1024,9) f32
  const int* mask = (const int*)d_in[2];         // (4,1024) int32
  Ws* ws = (Ws*)d_ws;
  float* out = (float*)d_out;

  prep_kernel<<<8, 512, 0, stream>>>(outputs, targets, mask, ws);
  dist_kernel<<<NROW / 4, 256, 0, stream>>>(outputs, targets, mask, ws);
  finalize_kernel<<<1, 256, 0, stream>>>(ws, out);
}